// Round 1
// baseline (267.991 us; speedup 1.0000x reference)
//
#include <hip/hip_runtime.h>
#include <hip/hip_bf16.h>

typedef short  short8  __attribute__((ext_vector_type(8)));
typedef float  f32x16  __attribute__((ext_vector_type(16)));

#define XB 16
#define XC 128
#define XH 64
#define XW 64
#define XHW 4096

__device__ __forceinline__ unsigned short f2bf(float f) {
    union { float f; unsigned int u; } v; v.f = f;
    unsigned int r = (v.u + 0x7fffu + ((v.u >> 16) & 1u)) >> 16;
    return (unsigned short)r;
}

// ---------------- K1: pooled mean over H,W of x[:, :64] ----------------
__global__ void k_pool(const float* __restrict__ x, float* __restrict__ pooled) {
    int bc = blockIdx.x;               // b*64 + c
    int b = bc >> 6, c = bc & 63;
    const float* p = x + (size_t)(b * XC + c) * XHW;
    int t = threadIdx.x;
    float s = 0.f;
#pragma unroll
    for (int k = 0; k < 16; ++k) s += p[t + k * 256];
    for (int off = 32; off > 0; off >>= 1) s += __shfl_down(s, off);
    __shared__ float ws[4];
    if ((t & 63) == 0) ws[t >> 6] = s;
    __syncthreads();
    if (t == 0) pooled[bc] = (ws[0] + ws[1] + ws[2] + ws[3]) * (1.f / 4096.f);
}

// ---------------- K2: tiny MLP -> dyn[B][64][9] ----------------
__global__ void k_mlp(const float* __restrict__ pooled,
                      const float* __restrict__ w1, const float* __restrict__ b1,
                      const float* __restrict__ w2, const float* __restrict__ b2,
                      float* __restrict__ dyn) {
    __shared__ float hbuf[512];
    int t = threadIdx.x;               // 576 threads
    if (t < 512) {
        int b = t >> 5, o = t & 31;
        float s = b1[o];
#pragma unroll
        for (int c = 0; c < 64; ++c) s += pooled[b * 64 + c] * w1[o * 64 + c];
        // exact gelu: x * 0.5 * (1 + erf(x/sqrt(2)))
        hbuf[b * 32 + o] = 0.5f * s * (1.f + erff(s * 0.70710678118654752f));
    }
    __syncthreads();
    for (int b = 0; b < 16; ++b) {
        float s = b2[t];
#pragma unroll
        for (int i = 0; i < 32; ++i) s += hbuf[b * 32 + i] * w2[t * 32 + i];
        dyn[b * 576 + t] = s;
    }
}

// ---------------- K3a: zero xpad ----------------
__global__ void k_zero(uint4* __restrict__ p, int n4) {
    int i = blockIdx.x * blockDim.x + threadIdx.x;
    int stride = gridDim.x * blockDim.x;
    uint4 z = {0u, 0u, 0u, 0u};
    for (; i < n4; i += stride) p[i] = z;
}

// ---------------- K3b: x[:, :64] NCHW fp32 -> xpad NHWC bf16 [16][76][76][64] ----------------
__global__ void k_xpad(const float* __restrict__ x, unsigned short* __restrict__ xpad) {
    __shared__ float tile[64][65];
    int blk = blockIdx.x;              // b*64 + h
    int b = blk >> 6, h = blk & 63;
    int t = threadIdx.x;
    {
        int w = t & 63, cg = t >> 6;   // cg 0..3
        const float* src = x + (size_t)b * XC * XHW + h * 64;
#pragma unroll
        for (int k = 0; k < 16; ++k) {
            int c = cg * 16 + k;
            tile[c][w] = src[(size_t)c * XHW + w];
        }
    }
    __syncthreads();
    {
        int pix = t >> 2, cp = t & 3;  // pix = w
        unsigned short tmp[16];
#pragma unroll
        for (int k = 0; k < 16; ++k) tmp[k] = f2bf(tile[cp * 16 + k][pix]);
        unsigned int u[8];
#pragma unroll
        for (int k = 0; k < 8; ++k) u[k] = (unsigned int)tmp[2 * k] | ((unsigned int)tmp[2 * k + 1] << 16);
        uint4 v0 = {u[0], u[1], u[2], u[3]};
        uint4 v1 = {u[4], u[5], u[6], u[7]};
        unsigned short* dst = xpad + ((size_t)(b * 76 + h + 6) * 76 + (pix + 6)) * 64 + cp * 16;
        *(uint4*)dst = v0;
        *((uint4*)dst + 1) = v1;
    }
}

// ---------------- K4: pack filter into B-fragment order ----------------
// fpack layout: frag(tap, ks, g): 64 lanes x 8 bf16 (1KB). value = f[oc=g*32+(l&31)][ic=ks*16+(l>>5)*8+e][tap]
__global__ void k_fpack(const float* __restrict__ lk, unsigned short* __restrict__ fpack) {
    int tidx = blockIdx.x * 256 + threadIdx.x;
    if (tidx >= 169 * 4 * 2 * 64) return;
    int l   = tidx & 63;
    int g   = (tidx >> 6) & 1;
    int ks  = (tidx >> 7) & 3;
    int tap = tidx >> 9;
    int oc  = g * 32 + (l & 31);
    int ic0 = ks * 16 + (l >> 5) * 8;
    unsigned short tmp[8];
#pragma unroll
    for (int e = 0; e < 8; ++e)
        tmp[e] = f2bf(lk[(size_t)(oc * 64 + ic0 + e) * 169 + tap]);
    unsigned int u[4];
#pragma unroll
    for (int k = 0; k < 4; ++k) u[k] = (unsigned int)tmp[2 * k] | ((unsigned int)tmp[2 * k + 1] << 16);
    uint4 v = {u[0], u[1], u[2], u[3]};
    *(uint4*)(fpack + (size_t)tidx * 8) = v;
}

// ---------------- K5: main 13x13 conv via 32x32x16 bf16 MFMA ----------------
// grid 512 = b(16) x th(4) x tw(8); tile 16x8 pixels, oc 0..63. 4 waves: wm=wave>>1 (pixel half), wn=wave&1 (oc half)
__global__ __launch_bounds__(256, 2) void k_conv(const unsigned short* __restrict__ xpad,
                                                 const unsigned short* __restrict__ fpack,
                                                 float* __restrict__ out) {
    extern __shared__ unsigned short lds[];   // [28][20][72] bf16, stride-padded
    int blk = blockIdx.x;
    int b = blk >> 5, tile = blk & 31;
    int th = tile >> 3, tw = tile & 7;
    int t = threadIdx.x;

    // ---- stage halo 28x20x64 into LDS ----
    const unsigned short* xbase = xpad + ((size_t)(b * 76 + th * 16) * 76 + tw * 8) * 64;
    for (int it = 0; it < 18; ++it) {
        int idx = it * 256 + t;               // pixel-part index; 560 pixels x 8 parts
        if (idx < 4480) {
            int pix = idx >> 3, part = idx & 7;
            int r = pix / 20, c = pix % 20;
            uint4 v = *(const uint4*)(xbase + ((size_t)r * 76 + c) * 64 + part * 8);
            *(uint4*)(lds + (r * 20 + c) * 72 + part * 8) = v;
        }
    }
    __syncthreads();

    int wave = t >> 6, l = t & 63;
    int wm = wave >> 1, wn = wave & 1;
    int l31 = l & 31, lhi = l >> 5;

    // A lane base (elements) for mf=0, tap(0,0), ks=0
    int abase0 = ((8 * wm + (l31 >> 3)) * 20 + (l31 & 7)) * 72 + lhi * 8;
    const unsigned short* fb = fpack + wn * 512 + l * 8;

    f32x16 acc0, acc1;
#pragma unroll
    for (int r = 0; r < 16; ++r) { acc0[r] = 0.f; acc1[r] = 0.f; }

#pragma unroll 1
    for (int i = 0; i < 13; ++i) {
        for (int j = 0; j < 13; ++j) {
            int tap = i * 13 + j;
            int aoff = abase0 + (i * 20 + j) * 72;
            const unsigned short* fbt = fb + (size_t)tap * 4096;
#pragma unroll
            for (int ks = 0; ks < 4; ++ks) {
                short8 bfrag = *(const short8*)(fbt + ks * 1024);
                short8 a0 = *(const short8*)(lds + aoff + ks * 16);
                short8 a1 = *(const short8*)(lds + aoff + 5760 + ks * 16);
                acc0 = __builtin_amdgcn_mfma_f32_32x32x16_bf16(a0, bfrag, acc0, 0, 0, 0);
                acc1 = __builtin_amdgcn_mfma_f32_32x32x16_bf16(a1, bfrag, acc1, 0, 0, 0);
            }
        }
    }

    // ---- epilogue: C/D layout: col=lane&31 -> oc, row=(reg&3)+8*(reg>>2)+4*(lane>>5) -> pixel
    int oc = wn * 32 + l31;
    float* obase = out + ((size_t)(b * XC + oc) * XH + th * 16) * XW + tw * 8;
#pragma unroll
    for (int r = 0; r < 16; ++r) {
        int p0 = (r & 3) + 8 * (r >> 2) + 4 * lhi;
        int pb0 = wm * 64 + p0;
        int pb1 = wm * 64 + 32 + p0;
        obase[(pb0 >> 3) * XW + (pb0 & 7)] = acc0[r];
        obase[(pb1 >> 3) * XW + (pb1 & 7)] = acc1[r];
    }
}

// ---------------- K6: add dynamic 3x3 depthwise part + copy x2 ----------------
__global__ void k_dyncopy(const float* __restrict__ x, const float* __restrict__ dyn,
                          float* __restrict__ out) {
    int idx = blockIdx.x * 256 + threadIdx.x;   // < 16*128*4096
    int w = idx & 63, h = (idx >> 6) & 63, c = (idx >> 12) & 127, b = idx >> 19;
    if (c >= 64) { out[idx] = x[idx]; return; }
    float s = out[idx];
    const float* dp = dyn + (b * 64 + c) * 9;
    const float* xp = x + (size_t)(b * XC + c) * XHW;
#pragma unroll
    for (int i = 0; i < 3; ++i) {
        int hh = h + i - 1;
        if ((unsigned)hh >= 64u) continue;
#pragma unroll
        for (int j = 0; j < 3; ++j) {
            int ww = w + j - 1;
            if ((unsigned)ww >= 64u) continue;
            s += dp[i * 3 + j] * xp[hh * 64 + ww];
        }
    }
    out[idx] = s;
}

extern "C" void kernel_launch(void* const* d_in, const int* in_sizes, int n_in,
                              void* d_out, int out_size, void* d_ws, size_t ws_size,
                              hipStream_t stream) {
    const float* x  = (const float*)d_in[0];
    const float* lk = (const float*)d_in[1];
    const float* w1 = (const float*)d_in[2];
    const float* b1 = (const float*)d_in[3];
    const float* w2 = (const float*)d_in[4];
    const float* b2 = (const float*)d_in[5];
    float* out = (float*)d_out;

    char* ws = (char*)d_ws;
    float*          pooled = (float*)ws;                                  //      4,096 B
    float*          dyn    = (float*)(ws + 4096);                         //     36,864 B
    unsigned short* fpack  = (unsigned short*)(ws + 4096 + 36864);        //  1,384,448 B
    unsigned short* xpad   = (unsigned short*)(ws + 4096 + 36864 + 1384448); // 11,829,248 B

    k_pool<<<1024, 256, 0, stream>>>(x, pooled);
    k_mlp<<<1, 576, 0, stream>>>(pooled, w1, b1, w2, b2, dyn);
    k_zero<<<2048, 256, 0, stream>>>((uint4*)xpad, 739328);
    k_xpad<<<1024, 256, 0, stream>>>(x, xpad);
    k_fpack<<<(86528 + 255) / 256, 256, 0, stream>>>(lk, fpack);
    k_conv<<<512, 256, 80640, stream>>>(xpad, fpack, out);
    k_dyncopy<<<32768, 256, 0, stream>>>(x, dyn, out);
}

// Round 4
// 263.888 us; speedup vs baseline: 1.0156x; 1.0156x over previous
//
#include <hip/hip_runtime.h>
#include <hip/hip_bf16.h>

typedef short  short8  __attribute__((ext_vector_type(8)));
typedef float  f32x16  __attribute__((ext_vector_type(16)));

#define XB 16
#define XC 128
#define XH 64
#define XW 64
#define XHW 4096
#define PSTR 72            // padded elems per pixel (64 data + 8 pad), 144 B
#define XPROW 76           // padded image width/height

__device__ __forceinline__ unsigned short f2bf(float f) {
    union { float f; unsigned int u; } v; v.f = f;
    unsigned int r = (v.u + 0x7fffu + ((v.u >> 16) & 1u)) >> 16;
    return (unsigned short)r;
}

// ---------------- K1: pooled mean over H,W of x[:, :64] ----------------
__global__ void k_pool(const float* __restrict__ x, float* __restrict__ pooled) {
    int bc = blockIdx.x;               // b*64 + c
    int b = bc >> 6, c = bc & 63;
    const float* p = x + (size_t)(b * XC + c) * XHW;
    int t = threadIdx.x;
    float s = 0.f;
#pragma unroll
    for (int k = 0; k < 16; ++k) s += p[t + k * 256];
    for (int off = 32; off > 0; off >>= 1) s += __shfl_down(s, off);
    __shared__ float ws[4];
    if ((t & 63) == 0) ws[t >> 6] = s;
    __syncthreads();
    if (t == 0) pooled[bc] = (ws[0] + ws[1] + ws[2] + ws[3]) * (1.f / 4096.f);
}

// ---------------- K2: tiny MLP -> dyn[B][64][9] ----------------
__global__ void k_mlp(const float* __restrict__ pooled,
                      const float* __restrict__ w1, const float* __restrict__ b1,
                      const float* __restrict__ w2, const float* __restrict__ b2,
                      float* __restrict__ dyn) {
    __shared__ float hbuf[512];
    int t = threadIdx.x;               // 576 threads
    if (t < 512) {
        int b = t >> 5, o = t & 31;
        float s = b1[o];
#pragma unroll
        for (int c = 0; c < 64; ++c) s += pooled[b * 64 + c] * w1[o * 64 + c];
        hbuf[b * 32 + o] = 0.5f * s * (1.f + erff(s * 0.70710678118654752f));
    }
    __syncthreads();
    for (int b = 0; b < 16; ++b) {
        float s = b2[t];
#pragma unroll
        for (int i = 0; i < 32; ++i) s += hbuf[b * 32 + i] * w2[t * 32 + i];
        dyn[b * 576 + t] = s;
    }
}

// ---------------- K3a: zero xpad (borders must read as 0) ----------------
__global__ void k_zero(uint4* __restrict__ p, int n4) {
    int i = blockIdx.x * blockDim.x + threadIdx.x;
    int stride = gridDim.x * blockDim.x;
    uint4 z = {0u, 0u, 0u, 0u};
    for (; i < n4; i += stride) p[i] = z;
}

// ---------------- K3b: x[:, :64] NCHW fp32 -> xpad bf16 [16][76][76][72-stride] ----------------
__global__ void k_xpad(const float* __restrict__ x, unsigned short* __restrict__ xpad) {
    __shared__ float tile[64][65];
    int blk = blockIdx.x;              // b*64 + h
    int b = blk >> 6, h = blk & 63;
    int t = threadIdx.x;
    {
        int w = t & 63, cg = t >> 6;   // cg 0..3
        const float* src = x + (size_t)b * XC * XHW + h * 64;
#pragma unroll
        for (int k = 0; k < 16; ++k) {
            int c = cg * 16 + k;
            tile[c][w] = src[(size_t)c * XHW + w];
        }
    }
    __syncthreads();
    {
        int pix = t >> 2, cp = t & 3;  // pix = w
        unsigned short tmp[16];
#pragma unroll
        for (int k = 0; k < 16; ++k) tmp[k] = f2bf(tile[cp * 16 + k][pix]);
        unsigned int u[8];
#pragma unroll
        for (int k = 0; k < 8; ++k) u[k] = (unsigned int)tmp[2 * k] | ((unsigned int)tmp[2 * k + 1] << 16);
        uint4 v0 = {u[0], u[1], u[2], u[3]};
        uint4 v1 = {u[4], u[5], u[6], u[7]};
        unsigned short* dst = xpad + ((size_t)(b * XPROW + h + 6) * XPROW + (pix + 6)) * PSTR + cp * 16;
        *(uint4*)dst = v0;
        *((uint4*)dst + 1) = v1;
    }
}

// ---------------- K4: pack 13x13 filter into B-fragment order ----------------
// frag elem offset = tap*4096 + ks*1024 + g*512 + l*8; value f[oc=g*32+(l&31)][ic=ks*16+(l>>5)*8+e][tap]
__global__ void k_fpack(const float* __restrict__ lk, unsigned short* __restrict__ fpack) {
    int tidx = blockIdx.x * 256 + threadIdx.x;
    if (tidx >= 169 * 4 * 2 * 64) return;
    int l   = tidx & 63;
    int g   = (tidx >> 6) & 1;
    int ks  = (tidx >> 7) & 3;
    int tap = tidx >> 9;
    int oc  = g * 32 + (l & 31);
    int ic0 = ks * 16 + (l >> 5) * 8;
    unsigned short tmp[8];
#pragma unroll
    for (int e = 0; e < 8; ++e)
        tmp[e] = f2bf(lk[(size_t)(oc * 64 + ic0 + e) * 169 + tap]);
    unsigned int u[4];
#pragma unroll
    for (int k = 0; k < 4; ++k) u[k] = (unsigned int)tmp[2 * k] | ((unsigned int)tmp[2 * k + 1] << 16);
    uint4 v = {u[0], u[1], u[2], u[3]};
    *(uint4*)(fpack + (size_t)tidx * 8) = v;
}

// ---------------- K4b: per-image diagonal B-frags for the dynamic 3x3 ----------------
// dpack elem offset = tidx*8 where tidx = ((b*9+tp)*4 + ks)*128 + g*64 + l
__global__ void k_fpack_dyn(const float* __restrict__ dyn, unsigned short* __restrict__ dpack) {
    int tidx = blockIdx.x * 256 + threadIdx.x;   // < 73728
    int l   = tidx & 63;
    int g   = (tidx >> 6) & 1;
    int ks  = (tidx >> 7) & 3;
    int bt  = tidx >> 9;                 // b*9 + tp
    int b   = bt / 9;
    int tp  = bt - b * 9;
    int oc  = g * 32 + (l & 31);
    int ic0 = ks * 16 + (l >> 5) * 8;
    float dv = dyn[(b * 64 + oc) * 9 + tp];
    unsigned short tmp[8];
#pragma unroll
    for (int e = 0; e < 8; ++e)
        tmp[e] = (ic0 + e == oc) ? f2bf(dv) : (unsigned short)0;
    unsigned int u[4];
#pragma unroll
    for (int k = 0; k < 4; ++k) u[k] = (unsigned int)tmp[2 * k] | ((unsigned int)tmp[2 * k + 1] << 16);
    uint4 v = {u[0], u[1], u[2], u[3]};
    *(uint4*)(dpack + (size_t)tidx * 8) = v;
}

// ---------------- K5: main conv, tile 16x16, 4 waves, M=2 x N=2 per wave ----------------
__global__ __launch_bounds__(256, 1) void k_conv(const unsigned short* __restrict__ xpad,
                                                 const unsigned short* __restrict__ fpack,
                                                 const unsigned short* __restrict__ dpack,
                                                 const float* __restrict__ x,
                                                 float* __restrict__ out) {
    extern __shared__ unsigned short lds[];   // [28 rows][28 px][72] = 112,896 B
    int blk = blockIdx.x;                      // 256 = b(16) x th(4) x tw(4)
    int b = blk >> 4, tile = blk & 15;
    int th = tile >> 2, tw = tile & 3;
    int Y0 = th * 16, X0 = tw * 16;
    int t = threadIdx.x;

    // ---- stage halo 28x28 pixels (72-elem stride; 28*72 elems = 252 uint4 per row) ----
    {
        const unsigned short* srcb = xpad + ((size_t)(b * XPROW + Y0) * XPROW + X0) * PSTR;
        for (int r = 0; r < 28; ++r) {
            const unsigned short* src = srcb + (size_t)r * XPROW * PSTR;
            unsigned short* dst = lds + r * 28 * PSTR;
            if (t < 252)
                *(uint4*)(dst + t * 8) = *(const uint4*)(src + t * 8);
        }
    }
    __syncthreads();

    int wave = t >> 6, l = t & 63;
    int l31 = l & 31, lhi = l >> 5;

    // A base: pixel row = wave*4 + (l31>>3), col = (l31&7); second frag at +8 cols
    int abase = ((wave * 4 + (l31 >> 3)) * 28 + (l31 & 7)) * PSTR + lhi * 8;

    f32x16 acc00, acc01, acc10, acc11;
#pragma unroll
    for (int r = 0; r < 16; ++r) { acc00[r] = 0.f; acc01[r] = 0.f; acc10[r] = 0.f; acc11[r] = 0.f; }

    const unsigned short* fb = fpack + l * 8;

#pragma unroll 1
    for (int i = 0; i < 13; ++i) {
        const unsigned short* brow = fb + (size_t)(i * 13) * 4096;
        int arow = abase + i * 28 * PSTR;
#pragma unroll
        for (int j = 0; j < 13; ++j) {
            int aoff = arow + j * PSTR;
#pragma unroll
            for (int ks = 0; ks < 4; ++ks) {
                short8 b0 = *(const short8*)(brow + j * 4096 + ks * 1024);
                short8 b1 = *(const short8*)(brow + j * 4096 + ks * 1024 + 512);
                short8 a0 = *(const short8*)(lds + aoff + ks * 16);
                short8 a1 = *(const short8*)(lds + aoff + 8 * PSTR + ks * 16);
                acc00 = __builtin_amdgcn_mfma_f32_32x32x16_bf16(a0, b0, acc00, 0, 0, 0);
                acc01 = __builtin_amdgcn_mfma_f32_32x32x16_bf16(a0, b1, acc01, 0, 0, 0);
                acc10 = __builtin_amdgcn_mfma_f32_32x32x16_bf16(a1, b0, acc10, 0, 0, 0);
                acc11 = __builtin_amdgcn_mfma_f32_32x32x16_bf16(a1, b1, acc11, 0, 0, 0);
            }
        }
    }

    // ---- dynamic 3x3 as 9 per-image diagonal taps (offsets i=di+5, j=dj+5) ----
    {
        const unsigned short* db = dpack + (size_t)b * 9 * 4096 + l * 8;
#pragma unroll
        for (int di = 0; di < 3; ++di) {
#pragma unroll
            for (int dj = 0; dj < 3; ++dj) {
                int aoff = abase + ((di + 5) * 28 + (dj + 5)) * PSTR;
                const unsigned short* dtap = db + (size_t)(di * 3 + dj) * 4096;
#pragma unroll
                for (int ks = 0; ks < 4; ++ks) {
                    short8 b0 = *(const short8*)(dtap + ks * 1024);
                    short8 b1 = *(const short8*)(dtap + ks * 1024 + 512);
                    short8 a0 = *(const short8*)(lds + aoff + ks * 16);
                    short8 a1 = *(const short8*)(lds + aoff + 8 * PSTR + ks * 16);
                    acc00 = __builtin_amdgcn_mfma_f32_32x32x16_bf16(a0, b0, acc00, 0, 0, 0);
                    acc01 = __builtin_amdgcn_mfma_f32_32x32x16_bf16(a0, b1, acc01, 0, 0, 0);
                    acc10 = __builtin_amdgcn_mfma_f32_32x32x16_bf16(a1, b0, acc10, 0, 0, 0);
                    acc11 = __builtin_amdgcn_mfma_f32_32x32x16_bf16(a1, b1, acc11, 0, 0, 0);
                }
            }
        }
    }

    // ---- epilogue: C/D row p=(r&3)+8*(r>>2)+4*lhi -> pixel (p>>3, p&7); col l31 -> oc
    {
        int y0 = Y0 + wave * 4;
#pragma unroll
        for (int r = 0; r < 16; ++r) {
            int p = (r & 3) + 8 * (r >> 2) + 4 * lhi;
            int py = y0 + (p >> 3), px = (p & 7);
            size_t base0 = ((size_t)(b * XC + l31) * XH + py) * XW;
            size_t base1 = ((size_t)(b * XC + 32 + l31) * XH + py) * XW;
            out[base0 + X0 + px]     = acc00[r];
            out[base1 + X0 + px]     = acc01[r];
            out[base0 + X0 + 8 + px] = acc10[r];
            out[base1 + X0 + 8 + px] = acc11[r];
        }
    }

    // ---- fused copy of x[:, 64:128] -> out (HBM idle during compute) ----
    {
        const uint4* xs = (const uint4*)x;
        uint4* od = (uint4*)out;
#pragma unroll
        for (int q = 0; q < 16; ++q) {
            int m4 = (blk * 16 + q) * 256 + t;      // 0 .. 1,048,575
            int bi = m4 >> 16;
            int rem = m4 & 65535;
            size_t off = (size_t)bi * 131072 + 65536 + rem;
            od[off] = xs[off];
        }
    }
}

extern "C" void kernel_launch(void* const* d_in, const int* in_sizes, int n_in,
                              void* d_out, int out_size, void* d_ws, size_t ws_size,
                              hipStream_t stream) {
    const float* x  = (const float*)d_in[0];
    const float* lk = (const float*)d_in[1];
    const float* w1 = (const float*)d_in[2];
    const float* b1 = (const float*)d_in[3];
    const float* w2 = (const float*)d_in[4];
    const float* b2 = (const float*)d_in[5];
    float* out = (float*)d_out;

    char* ws = (char*)d_ws;
    float*          pooled = (float*)ws;                       //        4,096 B @ 0
    float*          dyn    = (float*)(ws + 4096);              //       36,864 B @ 4096
    unsigned short* fpack  = (unsigned short*)(ws + 40960);    //    1,384,448 B @ 40,960
    unsigned short* dpack  = (unsigned short*)(ws + 1425408);  //    1,179,648 B @ 1,425,408
    unsigned short* xpad   = (unsigned short*)(ws + 2605056);  //   13,307,904 B @ 2,605,056

    k_zero<<<2048, 256, 0, stream>>>((uint4*)xpad, 831744);
    k_pool<<<1024, 256, 0, stream>>>(x, pooled);
    k_mlp<<<1, 576, 0, stream>>>(pooled, w1, b1, w2, b2, dyn);
    k_xpad<<<1024, 256, 0, stream>>>(x, xpad);
    k_fpack<<<338, 256, 0, stream>>>(lk, fpack);
    k_fpack_dyn<<<288, 256, 0, stream>>>(dyn, dpack);
    k_conv<<<256, 256, 112896, stream>>>(xpad, fpack, dpack, x, out);
}

// Round 5
// 135.881 us; speedup vs baseline: 1.9722x; 1.9420x over previous
//
#include <hip/hip_runtime.h>
#include <hip/hip_bf16.h>

typedef short  short8  __attribute__((ext_vector_type(8)));
typedef float  f32x16  __attribute__((ext_vector_type(16)));

#define XB 16
#define XC 128
#define XH 64
#define XW 64
#define XHW 4096
#define PSTR 72            // padded elems per pixel (64 data + 8 pad), 144 B
#define XPROW 76           // padded image width/height

__device__ __forceinline__ unsigned short f2bf(float f) {
    union { float f; unsigned int u; } v; v.f = f;
    unsigned int r = (v.u + 0x7fffu + ((v.u >> 16) & 1u)) >> 16;
    return (unsigned short)r;
}

// ---------------- K1: pooled mean over H,W of x[:, :64] ----------------
__global__ void k_pool(const float* __restrict__ x, float* __restrict__ pooled) {
    int bc = blockIdx.x;               // b*64 + c
    int b = bc >> 6, c = bc & 63;
    const float* p = x + (size_t)(b * XC + c) * XHW;
    int t = threadIdx.x;
    float s = 0.f;
#pragma unroll
    for (int k = 0; k < 16; ++k) s += p[t + k * 256];
    for (int off = 32; off > 0; off >>= 1) s += __shfl_down(s, off);
    __shared__ float ws[4];
    if ((t & 63) == 0) ws[t >> 6] = s;
    __syncthreads();
    if (t == 0) pooled[bc] = (ws[0] + ws[1] + ws[2] + ws[3]) * (1.f / 4096.f);
}

// ---------------- K2: tiny MLP -> dyn[B][64][9] ----------------
__global__ void k_mlp(const float* __restrict__ pooled,
                      const float* __restrict__ w1, const float* __restrict__ b1,
                      const float* __restrict__ w2, const float* __restrict__ b2,
                      float* __restrict__ dyn) {
    __shared__ float hbuf[512];
    int t = threadIdx.x;               // 576 threads
    if (t < 512) {
        int b = t >> 5, o = t & 31;
        float s = b1[o];
#pragma unroll
        for (int c = 0; c < 64; ++c) s += pooled[b * 64 + c] * w1[o * 64 + c];
        hbuf[b * 32 + o] = 0.5f * s * (1.f + erff(s * 0.70710678118654752f));
    }
    __syncthreads();
    for (int b = 0; b < 16; ++b) {
        float s = b2[t];
#pragma unroll
        for (int i = 0; i < 32; ++i) s += hbuf[b * 32 + i] * w2[t * 32 + i];
        dyn[b * 576 + t] = s;
    }
}

// ---------------- K3a: zero xpad (borders must read as 0) ----------------
__global__ void k_zero(uint4* __restrict__ p, int n4) {
    int i = blockIdx.x * blockDim.x + threadIdx.x;
    int stride = gridDim.x * blockDim.x;
    uint4 z = {0u, 0u, 0u, 0u};
    for (; i < n4; i += stride) p[i] = z;
}

// ---------------- K3b: x[:, :64] NCHW fp32 -> xpad bf16 [16][76][76][72-stride] ----------------
__global__ void k_xpad(const float* __restrict__ x, unsigned short* __restrict__ xpad) {
    __shared__ float tile[64][65];
    int blk = blockIdx.x;              // b*64 + h
    int b = blk >> 6, h = blk & 63;
    int t = threadIdx.x;
    {
        int w = t & 63, cg = t >> 6;   // cg 0..3
        const float* src = x + (size_t)b * XC * XHW + h * 64;
#pragma unroll
        for (int k = 0; k < 16; ++k) {
            int c = cg * 16 + k;
            tile[c][w] = src[(size_t)c * XHW + w];
        }
    }
    __syncthreads();
    {
        int pix = t >> 2, cp = t & 3;  // pix = w
        unsigned short tmp[16];
#pragma unroll
        for (int k = 0; k < 16; ++k) tmp[k] = f2bf(tile[cp * 16 + k][pix]);
        unsigned int u[8];
#pragma unroll
        for (int k = 0; k < 8; ++k) u[k] = (unsigned int)tmp[2 * k] | ((unsigned int)tmp[2 * k + 1] << 16);
        uint4 v0 = {u[0], u[1], u[2], u[3]};
        uint4 v1 = {u[4], u[5], u[6], u[7]};
        unsigned short* dst = xpad + ((size_t)(b * XPROW + h + 6) * XPROW + (pix + 6)) * PSTR + cp * 16;
        *(uint4*)dst = v0;
        *((uint4*)dst + 1) = v1;
    }
}

// ---------------- K4: pack 13x13 filter into B-fragment order ----------------
// frag elem offset = tap*4096 + ks*1024 + g*512 + l*8; value f[oc=g*32+(l&31)][ic=ks*16+(l>>5)*8+e][tap]
__global__ void k_fpack(const float* __restrict__ lk, unsigned short* __restrict__ fpack) {
    int tidx = blockIdx.x * 256 + threadIdx.x;
    if (tidx >= 169 * 4 * 2 * 64) return;
    int l   = tidx & 63;
    int g   = (tidx >> 6) & 1;
    int ks  = (tidx >> 7) & 3;
    int tap = tidx >> 9;
    int oc  = g * 32 + (l & 31);
    int ic0 = ks * 16 + (l >> 5) * 8;
    unsigned short tmp[8];
#pragma unroll
    for (int e = 0; e < 8; ++e)
        tmp[e] = f2bf(lk[(size_t)(oc * 64 + ic0 + e) * 169 + tap]);
    unsigned int u[4];
#pragma unroll
    for (int k = 0; k < 4; ++k) u[k] = (unsigned int)tmp[2 * k] | ((unsigned int)tmp[2 * k + 1] << 16);
    uint4 v = {u[0], u[1], u[2], u[3]};
    *(uint4*)(fpack + (size_t)tidx * 8) = v;
}

// ---------------- K4b: per-image diagonal B-frags for the dynamic 3x3 ----------------
// dpack elem offset = tidx*8 where tidx = ((b*9+tp)*4 + ks)*128 + g*64 + l
__global__ void k_fpack_dyn(const float* __restrict__ dyn, unsigned short* __restrict__ dpack) {
    int tidx = blockIdx.x * 256 + threadIdx.x;   // < 73728
    int l   = tidx & 63;
    int g   = (tidx >> 6) & 1;
    int ks  = (tidx >> 7) & 3;
    int bt  = tidx >> 9;                 // b*9 + tp
    int b   = bt / 9;
    int tp  = bt - b * 9;
    int oc  = g * 32 + (l & 31);
    int ic0 = ks * 16 + (l >> 5) * 8;
    float dv = dyn[(b * 64 + oc) * 9 + tp];
    unsigned short tmp[8];
#pragma unroll
    for (int e = 0; e < 8; ++e)
        tmp[e] = (ic0 + e == oc) ? f2bf(dv) : (unsigned short)0;
    unsigned int u[4];
#pragma unroll
    for (int k = 0; k < 4; ++k) u[k] = (unsigned int)tmp[2 * k] | ((unsigned int)tmp[2 * k + 1] << 16);
    uint4 v = {u[0], u[1], u[2], u[3]};
    *(uint4*)(dpack + (size_t)tidx * 8) = v;
}

// ---------------- K5: main conv. tile 16x8, 4 waves ks-split, M4N2 per wave ----------------
// grid 512 = b(16) x th(4) x tw(8). LDS halo 28x20x72 = 80,640 B -> 2 blocks/CU.
// Wave w handles ic-chunk [16w,16w+16) for ALL taps; cross-wave partials reduced via LDS.
__global__ __launch_bounds__(256, 2) void k_conv(const unsigned short* __restrict__ xpad,
                                                 const unsigned short* __restrict__ fpack,
                                                 const unsigned short* __restrict__ dpack,
                                                 const float* __restrict__ x,
                                                 float* __restrict__ out) {
    extern __shared__ unsigned short lds[];   // 40,320 bf16 elems
    int blk = blockIdx.x;
    int b = blk >> 5, tile = blk & 31;
    int th = tile >> 3, tw = tile & 7;
    int Y0 = th * 16, X0 = tw * 8;
    int t = threadIdx.x;

    // ---- stage halo 28 rows x 20 px (72-elem stride; 180 uint4 per row) ----
    {
        const unsigned short* srcb = xpad + ((size_t)(b * XPROW + Y0) * XPROW + X0) * PSTR;
        for (int k = t; k < 5040; k += 256) {
            int r = k / 180, o = k - r * 180;
            *(uint4*)(lds + r * 20 * PSTR + o * 8) =
                *(const uint4*)(srcb + (size_t)r * XPROW * PSTR + o * 8);
        }
    }
    __syncthreads();

    int wave = t >> 6, l = t & 63;     // wave = ks chunk
    int l31 = l & 31, lhi = l >> 5;

    // A base for m-frag 0, tap (0,0): pixel row=(l31>>3), col=(l31&7); m adds m*4 rows = m*5760 elems
    int abase = ((l31 >> 3) * 20 + (l31 & 7)) * PSTR + lhi * 8 + wave * 16;

    f32x16 acc[4][2];
#pragma unroll
    for (int m = 0; m < 4; ++m)
#pragma unroll
        for (int n = 0; n < 2; ++n)
#pragma unroll
            for (int r = 0; r < 16; ++r) acc[m][n][r] = 0.f;

    const unsigned short* fb = fpack + wave * 1024 + l * 8;

#pragma unroll 1
    for (int i = 0; i < 13; ++i) {
        const unsigned short* brow = fb + (size_t)(i * 13) * 4096;
        int arow = abase + i * 20 * PSTR;
#pragma unroll
        for (int j = 0; j < 13; ++j) {
            short8 b0 = *(const short8*)(brow + j * 4096);
            short8 b1 = *(const short8*)(brow + j * 4096 + 512);
            int aoff = arow + j * PSTR;
#pragma unroll
            for (int m = 0; m < 4; ++m) {
                short8 a = *(const short8*)(lds + aoff + m * 5760);
                acc[m][0] = __builtin_amdgcn_mfma_f32_32x32x16_bf16(a, b0, acc[m][0], 0, 0, 0);
                acc[m][1] = __builtin_amdgcn_mfma_f32_32x32x16_bf16(a, b1, acc[m][1], 0, 0, 0);
            }
        }
    }

    // ---- dynamic 3x3 (taps at offsets i=di+5, j=dj+5), same ks-split ----
    {
        const unsigned short* db = dpack + (size_t)b * 9 * 4096 + wave * 1024 + l * 8;
#pragma unroll
        for (int di = 0; di < 3; ++di)
#pragma unroll
            for (int dj = 0; dj < 3; ++dj) {
                const unsigned short* dtap = db + (size_t)(di * 3 + dj) * 4096;
                short8 b0 = *(const short8*)(dtap);
                short8 b1 = *(const short8*)(dtap + 512);
                int aoff = abase + ((di + 5) * 20 + (dj + 5)) * PSTR;
#pragma unroll
                for (int m = 0; m < 4; ++m) {
                    short8 a = *(const short8*)(lds + aoff + m * 5760);
                    acc[m][0] = __builtin_amdgcn_mfma_f32_32x32x16_bf16(a, b0, acc[m][0], 0, 0, 0);
                    acc[m][1] = __builtin_amdgcn_mfma_f32_32x32x16_bf16(a, b1, acc[m][1], 0, 0, 0);
                }
            }
    }
    __syncthreads();   // all waves done reading halo

    // ---- cross-wave reduction (over ks chunks) via LDS, 4 rounds of 32KB ----
    float* lf = (float*)lds;
#pragma unroll
    for (int m = 0; m < 4; ++m) {
#pragma unroll
        for (int n = 0; n < 2; ++n)
#pragma unroll
            for (int r = 0; r < 16; ++r)
                lf[wave * 2048 + n * 1024 + r * 64 + l] = acc[m][n][r];
        __syncthreads();
        for (int k2 = 0; k2 < 8; ++k2) {
            int e = k2 * 256 + t;
            float s = lf[e] + lf[2048 + e] + lf[4096 + e] + lf[6144 + e];
            int n = e >> 10, r = (e >> 6) & 15, l2 = e & 63;
            int p = (r & 3) + 8 * (r >> 2) + 4 * (l2 >> 5);
            int y = Y0 + m * 4 + (p >> 3), xx = X0 + (p & 7);
            int oc = n * 32 + (l2 & 31);
            out[((size_t)(b * XC + oc) * XH + y) * XW + xx] = s;
        }
        __syncthreads();
    }

    // ---- fused copy of x[:, 64:128] -> out ----
    {
        const uint4* xs = (const uint4*)x;
        uint4* od = (uint4*)out;
#pragma unroll
        for (int q = 0; q < 8; ++q) {
            int m4 = blk * 2048 + q * 256 + t;      // 0 .. 1,048,575
            int bi = m4 >> 16;
            int rem = m4 & 65535;
            size_t off = (size_t)bi * 131072 + 65536 + rem;
            od[off] = xs[off];
        }
    }
}

extern "C" void kernel_launch(void* const* d_in, const int* in_sizes, int n_in,
                              void* d_out, int out_size, void* d_ws, size_t ws_size,
                              hipStream_t stream) {
    const float* x  = (const float*)d_in[0];
    const float* lk = (const float*)d_in[1];
    const float* w1 = (const float*)d_in[2];
    const float* b1 = (const float*)d_in[3];
    const float* w2 = (const float*)d_in[4];
    const float* b2 = (const float*)d_in[5];
    float* out = (float*)d_out;

    char* ws = (char*)d_ws;
    float*          pooled = (float*)ws;                       //        4,096 B @ 0
    float*          dyn    = (float*)(ws + 4096);              //       36,864 B @ 4096
    unsigned short* fpack  = (unsigned short*)(ws + 40960);    //    1,384,448 B @ 40,960
    unsigned short* dpack  = (unsigned short*)(ws + 1425408);  //    1,179,648 B @ 1,425,408
    unsigned short* xpad   = (unsigned short*)(ws + 2605056);  //   13,307,904 B @ 2,605,056

    k_zero<<<2048, 256, 0, stream>>>((uint4*)xpad, 831744);
    k_pool<<<1024, 256, 0, stream>>>(x, pooled);
    k_mlp<<<1, 576, 0, stream>>>(pooled, w1, b1, w2, b2, dyn);
    k_xpad<<<1024, 256, 0, stream>>>(x, xpad);
    k_fpack<<<338, 256, 0, stream>>>(lk, fpack);
    k_fpack_dyn<<<288, 256, 0, stream>>>(dyn, dpack);
    k_conv<<<512, 256, 80640, stream>>>(xpad, fpack, dpack, x, out);
}

// Round 6
// 130.493 us; speedup vs baseline: 2.0537x; 1.0413x over previous
//
#include <hip/hip_runtime.h>
#include <hip/hip_bf16.h>

typedef short  short8  __attribute__((ext_vector_type(8)));
typedef float  f32x16  __attribute__((ext_vector_type(16)));

#define XB 16
#define XC 128
#define XH 64
#define XW 64
#define XHW 4096
#define PSTR 72            // padded elems per pixel (64 data + 8 pad), 144 B
#define XPROW 76           // padded image width/height

__device__ __forceinline__ unsigned short f2bf(float f) {
    union { float f; unsigned int u; } v; v.f = f;
    unsigned int r = (v.u + 0x7fffu + ((v.u >> 16) & 1u)) >> 16;
    return (unsigned short)r;
}

// ---------------- K1: pooled mean over H,W of x[:, :64] ----------------
__global__ void k_pool(const float* __restrict__ x, float* __restrict__ pooled) {
    int bc = blockIdx.x;               // b*64 + c
    int b = bc >> 6, c = bc & 63;
    const float* p = x + (size_t)(b * XC + c) * XHW;
    int t = threadIdx.x;
    float s = 0.f;
#pragma unroll
    for (int k = 0; k < 16; ++k) s += p[t + k * 256];
    for (int off = 32; off > 0; off >>= 1) s += __shfl_down(s, off);
    __shared__ float ws[4];
    if ((t & 63) == 0) ws[t >> 6] = s;
    __syncthreads();
    if (t == 0) pooled[bc] = (ws[0] + ws[1] + ws[2] + ws[3]) * (1.f / 4096.f);
}

// ---------------- K2: tiny MLP -> dyn[B][64][9] ----------------
__global__ void k_mlp(const float* __restrict__ pooled,
                      const float* __restrict__ w1, const float* __restrict__ b1,
                      const float* __restrict__ w2, const float* __restrict__ b2,
                      float* __restrict__ dyn) {
    __shared__ float hbuf[512];
    int t = threadIdx.x;               // 576 threads
    if (t < 512) {
        int b = t >> 5, o = t & 31;
        float s = b1[o];
#pragma unroll
        for (int c = 0; c < 64; ++c) s += pooled[b * 64 + c] * w1[o * 64 + c];
        hbuf[b * 32 + o] = 0.5f * s * (1.f + erff(s * 0.70710678118654752f));
    }
    __syncthreads();
    for (int b = 0; b < 16; ++b) {
        float s = b2[t];
#pragma unroll
        for (int i = 0; i < 32; ++i) s += hbuf[b * 32 + i] * w2[t * 32 + i];
        dyn[b * 576 + t] = s;
    }
}

// ---------------- K3a: zero xpad (borders must read as 0) ----------------
__global__ void k_zero(uint4* __restrict__ p, int n4) {
    int i = blockIdx.x * blockDim.x + threadIdx.x;
    int stride = gridDim.x * blockDim.x;
    uint4 z = {0u, 0u, 0u, 0u};
    for (; i < n4; i += stride) p[i] = z;
}

// ---------------- K3b: x[:, :64] NCHW fp32 -> xpad bf16 [16][76][76][72-stride] ----------------
__global__ void k_xpad(const float* __restrict__ x, unsigned short* __restrict__ xpad) {
    __shared__ float tile[64][65];
    int blk = blockIdx.x;              // b*64 + h
    int b = blk >> 6, h = blk & 63;
    int t = threadIdx.x;
    {
        int w = t & 63, cg = t >> 6;   // cg 0..3
        const float* src = x + (size_t)b * XC * XHW + h * 64;
#pragma unroll
        for (int k = 0; k < 16; ++k) {
            int c = cg * 16 + k;
            tile[c][w] = src[(size_t)c * XHW + w];
        }
    }
    __syncthreads();
    {
        int pix = t >> 2, cp = t & 3;  // pix = w
        unsigned short tmp[16];
#pragma unroll
        for (int k = 0; k < 16; ++k) tmp[k] = f2bf(tile[cp * 16 + k][pix]);
        unsigned int u[8];
#pragma unroll
        for (int k = 0; k < 8; ++k) u[k] = (unsigned int)tmp[2 * k] | ((unsigned int)tmp[2 * k + 1] << 16);
        uint4 v0 = {u[0], u[1], u[2], u[3]};
        uint4 v1 = {u[4], u[5], u[6], u[7]};
        unsigned short* dst = xpad + ((size_t)(b * XPROW + h + 6) * XPROW + (pix + 6)) * PSTR + cp * 16;
        *(uint4*)dst = v0;
        *((uint4*)dst + 1) = v1;
    }
}

// ---------------- K4: pack 13x13 filter into B-fragment order ----------------
// frag elem offset = tap*4096 + ks*1024 + g*512 + l*8; value f[oc=g*32+(l&31)][ic=ks*16+(l>>5)*8+e][tap]
__global__ void k_fpack(const float* __restrict__ lk, unsigned short* __restrict__ fpack) {
    int tidx = blockIdx.x * 256 + threadIdx.x;
    if (tidx >= 169 * 4 * 2 * 64) return;
    int l   = tidx & 63;
    int g   = (tidx >> 6) & 1;
    int ks  = (tidx >> 7) & 3;
    int tap = tidx >> 9;
    int oc  = g * 32 + (l & 31);
    int ic0 = ks * 16 + (l >> 5) * 8;
    unsigned short tmp[8];
#pragma unroll
    for (int e = 0; e < 8; ++e)
        tmp[e] = f2bf(lk[(size_t)(oc * 64 + ic0 + e) * 169 + tap]);
    unsigned int u[4];
#pragma unroll
    for (int k = 0; k < 4; ++k) u[k] = (unsigned int)tmp[2 * k] | ((unsigned int)tmp[2 * k + 1] << 16);
    uint4 v = {u[0], u[1], u[2], u[3]};
    *(uint4*)(fpack + (size_t)tidx * 8) = v;
}

// ---------------- K4b: per-image diagonal B-frags for the dynamic 3x3 ----------------
// dpack elem offset = tidx*8 where tidx = ((b*9+tp)*4 + ks)*128 + g*64 + l
__global__ void k_fpack_dyn(const float* __restrict__ dyn, unsigned short* __restrict__ dpack) {
    int tidx = blockIdx.x * 256 + threadIdx.x;   // < 73728
    int l   = tidx & 63;
    int g   = (tidx >> 6) & 1;
    int ks  = (tidx >> 7) & 3;
    int bt  = tidx >> 9;                 // b*9 + tp
    int b   = bt / 9;
    int tp  = bt - b * 9;
    int oc  = g * 32 + (l & 31);
    int ic0 = ks * 16 + (l >> 5) * 8;
    float dv = dyn[(b * 64 + oc) * 9 + tp];
    unsigned short tmp[8];
#pragma unroll
    for (int e = 0; e < 8; ++e)
        tmp[e] = (ic0 + e == oc) ? f2bf(dv) : (unsigned short)0;
    unsigned int u[4];
#pragma unroll
    for (int k = 0; k < 4; ++k) u[k] = (unsigned int)tmp[2 * k] | ((unsigned int)tmp[2 * k + 1] << 16);
    uint4 v = {u[0], u[1], u[2], u[3]};
    *(uint4*)(dpack + (size_t)tidx * 8) = v;
}

// ---- batched tap group: load B frags for N taps into registers, then MFMA ----
template<int N>
__device__ __forceinline__ void conv_batch(const unsigned short* __restrict__ brow, int j0,
                                           const unsigned short* lds_p, int arow,
                                           f32x16 (&acc)[4][2]) {
    short8 B0[N], B1[N];
#pragma unroll
    for (int u = 0; u < N; ++u) {
        B0[u] = *(const short8*)(brow + (size_t)(j0 + u) * 4096);
        B1[u] = *(const short8*)(brow + (size_t)(j0 + u) * 4096 + 512);
    }
#pragma unroll
    for (int u = 0; u < N; ++u) {
        int aoff = arow + (j0 + u) * PSTR;
#pragma unroll
        for (int m = 0; m < 4; ++m) {
            short8 a = *(const short8*)(lds_p + aoff + m * 5760);
            acc[m][0] = __builtin_amdgcn_mfma_f32_32x32x16_bf16(a, B0[u], acc[m][0], 0, 0, 0);
            acc[m][1] = __builtin_amdgcn_mfma_f32_32x32x16_bf16(a, B1[u], acc[m][1], 0, 0, 0);
        }
    }
}

// ---------------- K5: main conv. tile 16x8, 4 waves ks-split, M4N2 per wave ----------------
// grid 512 = b(16) x th(4) x tw(8). LDS halo 28x20x72 = 80,640 B -> 2 blocks/CU.
__global__ __launch_bounds__(256, 2) void k_conv(const unsigned short* __restrict__ xpad,
                                                 const unsigned short* __restrict__ fpack,
                                                 const unsigned short* __restrict__ dpack,
                                                 const float* __restrict__ x,
                                                 float* __restrict__ out) {
    extern __shared__ unsigned short lds[];   // 40,320 bf16 elems
    int blk = blockIdx.x;
    int b = blk >> 5, tile = blk & 31;
    int th = tile >> 3, tw = tile & 7;
    int Y0 = th * 16, X0 = tw * 8;
    int t = threadIdx.x;

    // ---- stage halo 28 rows x 20 px (72-elem stride; 180 uint4 per row) ----
    {
        const unsigned short* srcb = xpad + ((size_t)(b * XPROW + Y0) * XPROW + X0) * PSTR;
        for (int k = t; k < 5040; k += 256) {
            int r = k / 180, o = k - r * 180;
            *(uint4*)(lds + r * 20 * PSTR + o * 8) =
                *(const uint4*)(srcb + (size_t)r * XPROW * PSTR + o * 8);
        }
    }
    __syncthreads();

    int wave = t >> 6, l = t & 63;     // wave = ks chunk
    int l31 = l & 31, lhi = l >> 5;

    int abase = ((l31 >> 3) * 20 + (l31 & 7)) * PSTR + lhi * 8 + wave * 16;

    f32x16 acc[4][2];
#pragma unroll
    for (int m = 0; m < 4; ++m)
#pragma unroll
        for (int n = 0; n < 2; ++n)
#pragma unroll
            for (int r = 0; r < 16; ++r) acc[m][n][r] = 0.f;

    const unsigned short* fb = fpack + wave * 1024 + l * 8;

#pragma unroll 1
    for (int i = 0; i < 13; ++i) {
        const unsigned short* brow = fb + (size_t)(i * 13) * 4096;
        int arow = abase + i * 20 * PSTR;
        conv_batch<5>(brow, 0, lds, arow, acc);
        conv_batch<4>(brow, 5, lds, arow, acc);
        conv_batch<4>(brow, 9, lds, arow, acc);
    }

    // ---- dynamic 3x3 (taps at offsets i=di+5, j=dj+5), batched per di-row ----
    {
        const unsigned short* db = dpack + (size_t)b * 9 * 4096 + wave * 1024 + l * 8;
#pragma unroll
        for (int di = 0; di < 3; ++di) {
            short8 B0[3], B1[3];
#pragma unroll
            for (int dj = 0; dj < 3; ++dj) {
                B0[dj] = *(const short8*)(db + (size_t)(di * 3 + dj) * 4096);
                B1[dj] = *(const short8*)(db + (size_t)(di * 3 + dj) * 4096 + 512);
            }
#pragma unroll
            for (int dj = 0; dj < 3; ++dj) {
                int aoff = abase + ((di + 5) * 20 + (dj + 5)) * PSTR;
#pragma unroll
                for (int m = 0; m < 4; ++m) {
                    short8 a = *(const short8*)(lds + aoff + m * 5760);
                    acc[m][0] = __builtin_amdgcn_mfma_f32_32x32x16_bf16(a, B0[dj], acc[m][0], 0, 0, 0);
                    acc[m][1] = __builtin_amdgcn_mfma_f32_32x32x16_bf16(a, B1[dj], acc[m][1], 0, 0, 0);
                }
            }
        }
    }
    __syncthreads();   // all waves done reading halo

    // ---- cross-wave reduction via LDS, layout lf[wave][oc(64)][p(32) pitch 33] ----
    float* lf = (float*)lds;
#pragma unroll
    for (int m = 0; m < 4; ++m) {
#pragma unroll
        for (int n = 0; n < 2; ++n)
#pragma unroll
            for (int r = 0; r < 16; ++r) {
                int oc = n * 32 + l31;
                int p  = (r & 3) + 8 * (r >> 2) + 4 * lhi;
                lf[wave * 2112 + oc * 33 + p] = acc[m][n][r];
            }
        __syncthreads();
#pragma unroll
        for (int k2 = 0; k2 < 8; ++k2) {
            int e = k2 * 256 + t;          // 0..2047
            int oc = e >> 5, p = e & 31;
            int idx = oc * 33 + p;
            float s = lf[idx] + lf[2112 + idx] + lf[4224 + idx] + lf[6336 + idx];
            int y = Y0 + m * 4 + (p >> 3), xx = X0 + (p & 7);
            out[((size_t)(b * XC + oc) * XH + y) * XW + xx] = s;
        }
        __syncthreads();
    }

    // ---- fused copy of x[:, 64:128] -> out ----
    {
        const uint4* xs = (const uint4*)x;
        uint4* od = (uint4*)out;
#pragma unroll
        for (int q = 0; q < 8; ++q) {
            int m4 = blk * 2048 + q * 256 + t;      // 0 .. 1,048,575
            int bi = m4 >> 16;
            int rem = m4 & 65535;
            size_t off = (size_t)bi * 131072 + 65536 + rem;
            od[off] = xs[off];
        }
    }
}

extern "C" void kernel_launch(void* const* d_in, const int* in_sizes, int n_in,
                              void* d_out, int out_size, void* d_ws, size_t ws_size,
                              hipStream_t stream) {
    const float* x  = (const float*)d_in[0];
    const float* lk = (const float*)d_in[1];
    const float* w1 = (const float*)d_in[2];
    const float* b1 = (const float*)d_in[3];
    const float* w2 = (const float*)d_in[4];
    const float* b2 = (const float*)d_in[5];
    float* out = (float*)d_out;

    char* ws = (char*)d_ws;
    float*          pooled = (float*)ws;                       //        4,096 B @ 0
    float*          dyn    = (float*)(ws + 4096);              //       36,864 B @ 4096
    unsigned short* fpack  = (unsigned short*)(ws + 40960);    //    1,384,448 B @ 40,960
    unsigned short* dpack  = (unsigned short*)(ws + 1425408);  //    1,179,648 B @ 1,425,408
    unsigned short* xpad   = (unsigned short*)(ws + 2605056);  //   13,307,904 B @ 2,605,056

    k_zero<<<2048, 256, 0, stream>>>((uint4*)xpad, 831744);
    k_pool<<<1024, 256, 0, stream>>>(x, pooled);
    k_mlp<<<1, 576, 0, stream>>>(pooled, w1, b1, w2, b2, dyn);
    k_xpad<<<1024, 256, 0, stream>>>(x, xpad);
    k_fpack<<<338, 256, 0, stream>>>(lk, fpack);
    k_fpack_dyn<<<288, 256, 0, stream>>>(dyn, dpack);
    k_conv<<<512, 256, 80640, stream>>>(xpad, fpack, dpack, x, out);
}